// Round 4
// baseline (313.012 us; speedup 1.0000x reference)
//
#include <hip/hip_runtime.h>
#include <hip/hip_bf16.h>
#include <hip/hip_fp16.h>

#define EMBED 640
#define CROSS 768
#define NH 8
#define HEAD 80
#define BATCH 8
#define SEQT 4096
#define SEQS 77
#define MROWS (BATCH * SEQT)

typedef _Float16 half8 __attribute__((ext_vector_type(8)));
typedef float floatx4 __attribute__((ext_vector_type(4)));

__device__ __forceinline__ void lds_load16(const void* g, void* l) {
    __builtin_amdgcn_global_load_lds(
        (const __attribute__((address_space(1))) void*)g,
        (__attribute__((address_space(3))) void*)l, 16, 0, 0);
}

// ---------------------------------------------------------------------------
// All four weight transposes in one launch. z: 0=Wq 1=Wo 2=Wk 3=Wv.
// W [K,N] fp32 -> Wt [N,K] f16 (tiled 32x32).
// ---------------------------------------------------------------------------
__global__ __launch_bounds__(256) void transpose_all(
    const float* __restrict__ Wq, const float* __restrict__ Wo,
    const float* __restrict__ Wk, const float* __restrict__ Wv,
    _Float16* __restrict__ wqt, _Float16* __restrict__ wot,
    _Float16* __restrict__ wkt, _Float16* __restrict__ wvt)
{
    __shared__ float t[32][33];
    const int z = blockIdx.z;
    const float* W;  _Float16* Wt;  int K;
    if      (z == 0) { W = Wq; Wt = wqt; K = EMBED; }
    else if (z == 1) { W = Wo; Wt = wot; K = EMBED; }
    else if (z == 2) { W = Wk; Wt = wkt; K = CROSS; }
    else             { W = Wv; Wt = wvt; K = CROSS; }
    const int N = EMBED;
    const int k0 = blockIdx.y * 32, n0 = blockIdx.x * 32;
    if (k0 >= K) return;
    for (int r = threadIdx.y; r < 32; r += 8)
        t[r][threadIdx.x] = W[(size_t)(k0 + r) * N + n0 + threadIdx.x];
    __syncthreads();
    for (int r = threadIdx.y; r < 32; r += 8)
        Wt[(size_t)(n0 + r) * K + k0 + threadIdx.x] = (_Float16)t[threadIdx.x][r];
}

// ---------------------------------------------------------------------------
// y [616*768] fp32 -> yh [640][768] f16 (rows 616+ zeroed)  AND  vth zero.
// Grid exactly 440*256 threads = 61440 (yh) + 51200 (vth) 8-elem slots.
// ---------------------------------------------------------------------------
__global__ __launch_bounds__(256) void cvt_y_zero(
    const float* __restrict__ y, _Float16* __restrict__ yh,
    _Float16* __restrict__ vth)
{
    const size_t i = (size_t)blockIdx.x * 256 + threadIdx.x;
    if (i < (size_t)640 * CROSS / 8) {
        const size_t e = i * 8;
        half8 h = {};
        if (e < (size_t)BATCH * SEQS * CROSS) {
            float4 a = *(const float4*)&y[e];
            float4 b = *(const float4*)&y[e + 4];
            h[0] = (_Float16)a.x; h[1] = (_Float16)a.y;
            h[2] = (_Float16)a.z; h[3] = (_Float16)a.w;
            h[4] = (_Float16)b.x; h[5] = (_Float16)b.y;
            h[6] = (_Float16)b.z; h[7] = (_Float16)b.w;
        }
        *(half8*)&yh[e] = h;
    } else {
        const size_t j = (i - (size_t)640 * CROSS / 8) * 8;
        *(half8*)&vth[j] = (half8){};
    }
}

// ---------------------------------------------------------------------------
// f16 MFMA GEMM: C(fp32) = A[M,K] @ Bt[N,K]^T + bias.
// v5: ONE barrier per K-step; 3-buffer LDS; counted vmcnt(4) in steady state
//     (2 stage-tiles always in flight across the barrier). stage(t+2) after
//     the barrier overwrites buf (t-1)%3, whose readers retired their
//     ds_reads before MFMA(t-1) (compiler-enforced) hence before the barrier.
//     Keeps XCD-aware remap + chunk XOR swizzle (conflicts = 0).
// ---------------------------------------------------------------------------
__global__ __launch_bounds__(256) void gemm_f16(
    const _Float16* __restrict__ A,   // [M,K] f16
    const _Float16* __restrict__ Bt,  // [N,K] f16
    const float* __restrict__ bias,
    float* __restrict__ Cout, int M, int N, int K)
{
    __shared__ _Float16 As[3][128 * 32];
    __shared__ _Float16 Bs[3][128 * 32];

    const int tid  = threadIdx.x;
    const int wave = tid >> 6;
    const int lane = tid & 63;
    const int quad = lane >> 4;
    const int l16  = lane & 15;

    // XCD-aware remap: the gridDim.x n-tiles of one m-panel -> same XCD.
    const int l   = blockIdx.y * gridDim.x + blockIdx.x;
    const int inner = l >> 3;
    const int p   = (l & 7) + 8 * (inner / gridDim.x);
    const int nt  = inner % gridDim.x;
    const int m0 = p * 128, n0 = nt * 128;
    const int wm = (wave >> 1) * 64, wn = (wave & 1) * 64;

    const int row = tid >> 2;
    const int kch = ((tid & 3) ^ ((row >> 1) & 3)) * 8;   // pre-swizzled src
    const int cq  = (quad ^ ((l16 >> 1) & 3)) * 8;        // swizzled read

    const _Float16* pa0 = &A [(size_t)(m0 + row)      * K + kch];
    const _Float16* pa1 = &A [(size_t)(m0 + 64 + row) * K + kch];
    const _Float16* pb0 = &Bt[(size_t)(n0 + row)      * K + kch];
    const _Float16* pb1 = &Bt[(size_t)(n0 + 64 + row) * K + kch];

    const int NT = K / 32;   // 20

    auto stage = [&](int t) {
        const int bf = t % 3;
        const int off = t * 32;
        lds_load16(pa0 + off, &As[bf][wave * 512]);
        lds_load16(pa1 + off, &As[bf][2048 + wave * 512]);
        lds_load16(pb0 + off, &Bs[bf][wave * 512]);
        lds_load16(pb1 + off, &Bs[bf][2048 + wave * 512]);
    };
    stage(0); stage(1);      // 8 loads in flight

    floatx4 acc[4][4] = {};

    for (int t = 0; t < NT; ++t) {
        // my stage(t) landed; leave stage(t+1) in flight
        if (t < NT - 1) asm volatile("s_waitcnt vmcnt(4)" ::: "memory");
        else            asm volatile("s_waitcnt vmcnt(0)" ::: "memory");
        __builtin_amdgcn_s_barrier();   // all waves' stage(t) visible
        if (t + 2 < NT) stage(t + 2);   // overwrites buf (t-1)%3 (free)

        const _Float16* as = As[t % 3];
        const _Float16* bs = Bs[t % 3];
        half8 a[4], b[4];
        #pragma unroll
        for (int i = 0; i < 4; ++i)
            a[i] = *(const half8*)&as[(wm + i * 16 + l16) * 32 + cq];
        #pragma unroll
        for (int j = 0; j < 4; ++j)
            b[j] = *(const half8*)&bs[(wn + j * 16 + l16) * 32 + cq];
        #pragma unroll
        for (int i = 0; i < 4; ++i)
            #pragma unroll
            for (int j = 0; j < 4; ++j)
                acc[i][j] = __builtin_amdgcn_mfma_f32_16x16x32_f16(
                    a[i], b[j], acc[i][j], 0, 0, 0);
    }

    float bcol[4];
    #pragma unroll
    for (int j = 0; j < 4; ++j) bcol[j] = bias[n0 + wn + j * 16 + l16];
    #pragma unroll
    for (int i = 0; i < 4; ++i)
        #pragma unroll
        for (int r = 0; r < 4; ++r) {
            const int m = m0 + wm + i * 16 + quad * 4 + r;
            #pragma unroll
            for (int j = 0; j < 4; ++j)
                Cout[(size_t)m * N + n0 + wn + j * 16 + l16] =
                    acc[i][j][r] + bcol[j];
        }
}

// ---------------------------------------------------------------------------
// Q projection with fused fp32->f16 cast of x.
// A = x fp32 [M][640]: reg-staged (float4 x4 -> cvt -> swizzled ds_write).
// B = wqt f16 via global_load_lds. 2-phase single-barrier loop: next-tile
// loads issued at top, vmcnt(0) drained under ds_read+MFMA of current tile.
// Out: qh f16 with 1/sqrt(80) folded.
// ---------------------------------------------------------------------------
__global__ __launch_bounds__(256) void gemm_q(
    const float* __restrict__ x,      // [M][EMBED] fp32
    const _Float16* __restrict__ Bt,  // [EMBED][EMBED] f16
    const float* __restrict__ bias,
    _Float16* __restrict__ Cout)      // [M][EMBED] f16
{
    constexpr int K = EMBED, N = EMBED;
    __shared__ _Float16 As[2][128 * 32];
    __shared__ _Float16 Bs[2][128 * 32];

    const int tid  = threadIdx.x;
    const int wave = tid >> 6;
    const int lane = tid & 63;
    const int quad = lane >> 4;
    const int l16  = lane & 15;

    const int l   = blockIdx.y * gridDim.x + blockIdx.x;
    const int inner = l >> 3;
    const int p   = (l & 7) + 8 * (inner / gridDim.x);
    const int nt  = inner % gridDim.x;
    const int m0 = p * 128, n0 = nt * 128;
    const int wm = (wave >> 1) * 64, wn = (wave & 1) * 64;

    // A reg-staging: 2 threads/row, 16 fp32 (= 2 f16-chunks) each.
    const int arow  = tid >> 1;
    const int ahalf = tid & 1;
    const int s_r   = (arow >> 1) & 3;
    const int slot0 = ((ahalf * 2)     ^ s_r) * 8;
    const int slot1 = ((ahalf * 2 + 1) ^ s_r) * 8;
    const float* gx = &x[(size_t)(m0 + arow) * K + ahalf * 16];

    // B staging via gload_lds with pre-swizzled source chunk.
    const int brow = tid >> 2;
    const int bkch = ((tid & 3) ^ ((brow >> 1) & 3)) * 8;
    const _Float16* gb0 = &Bt[(size_t)(n0 + brow)      * K + bkch];
    const _Float16* gb1 = &Bt[(size_t)(n0 + 64 + brow) * K + bkch];

    const int cq = (quad ^ ((l16 >> 1) & 3)) * 8;

    float4 f0, f1, f2, f3;
    auto loadA = [&](int t) {
        const float* gp = gx + t * 32;
        f0 = *(const float4*)gp;       f1 = *(const float4*)(gp + 4);
        f2 = *(const float4*)(gp + 8); f3 = *(const float4*)(gp + 12);
    };
    auto writeA = [&](int bf) {
        half8 h0, h1;
        h0[0] = (_Float16)f0.x; h0[1] = (_Float16)f0.y;
        h0[2] = (_Float16)f0.z; h0[3] = (_Float16)f0.w;
        h0[4] = (_Float16)f1.x; h0[5] = (_Float16)f1.y;
        h0[6] = (_Float16)f1.z; h0[7] = (_Float16)f1.w;
        h1[0] = (_Float16)f2.x; h1[1] = (_Float16)f2.y;
        h1[2] = (_Float16)f2.z; h1[3] = (_Float16)f2.w;
        h1[4] = (_Float16)f3.x; h1[5] = (_Float16)f3.y;
        h1[6] = (_Float16)f3.z; h1[7] = (_Float16)f3.w;
        *(half8*)&As[bf][arow * 32 + slot0] = h0;
        *(half8*)&As[bf][arow * 32 + slot1] = h1;
    };
    auto loadB = [&](int t, int bf) {
        lds_load16(gb0 + t * 32, &Bs[bf][wave * 512]);
        lds_load16(gb1 + t * 32, &Bs[bf][2048 + wave * 512]);
    };

    constexpr int NT = K / 32;   // 20

    // prologue: tile 0
    loadB(0, 0); loadA(0);
    asm volatile("s_waitcnt vmcnt(0)" ::: "memory");
    writeA(0);
    asm volatile("s_waitcnt lgkmcnt(0)" ::: "memory");
    __builtin_amdgcn_s_barrier();

    floatx4 acc[4][4] = {};
    int cur = 0;

    for (int t = 0; t < NT; ++t) {
        if (t + 1 < NT) { loadB(t + 1, cur ^ 1); loadA(t + 1); }

        const _Float16* as = As[cur];
        const _Float16* bs = Bs[cur];
        half8 a[4], b[4];
        #pragma unroll
        for (int i = 0; i < 4; ++i)
            a[i] = *(const half8*)&as[(wm + i * 16 + l16) * 32 + cq];
        #pragma unroll
        for (int j = 0; j < 4; ++j)
            b[j] = *(const half8*)&bs[(wn + j * 16 + l16) * 32 + cq];
        #pragma unroll
        for (int i = 0; i < 4; ++i)
            #pragma unroll
            for (int j = 0; j < 4; ++j)
                acc[i][j] = __builtin_amdgcn_mfma_f32_16x16x32_f16(
                    a[i], b[j], acc[i][j], 0, 0, 0);

        if (t + 1 < NT) {
            asm volatile("s_waitcnt vmcnt(0)" ::: "memory");  // A regs + B lds
            writeA(cur ^ 1);
            asm volatile("s_waitcnt lgkmcnt(0)" ::: "memory");
        }
        __builtin_amdgcn_s_barrier();
        cur ^= 1;
    }

    const float scale = 0.11180339887498949f;   // 1/sqrt(80)
    float bcol[4];
    #pragma unroll
    for (int j = 0; j < 4; ++j) bcol[j] = bias[n0 + wn + j * 16 + l16];
    #pragma unroll
    for (int i = 0; i < 4; ++i)
        #pragma unroll
        for (int r = 0; r < 4; ++r) {
            const int m = m0 + wm + i * 16 + quad * 4 + r;
            #pragma unroll
            for (int j = 0; j < 4; ++j)
                Cout[(size_t)m * N + n0 + wn + j * 16 + l16] =
                    (_Float16)((acc[i][j][r] + bcol[j]) * scale);
        }
}

// ---------------------------------------------------------------------------
// K/V projection via MFMA. 64x64 tiles, 4 waves (wave w = cols w*16..w*16+15).
// A = yh [640][768] f16 (rows 616+ zero), B = Wkt/Wvt [640][768] f16.
// Epilogue scatters f16 into attention layouts:
//   kh [bh][s(77)][d(80)], vth[bh][d(80)][s(80, pads pre-zeroed)]
// ---------------------------------------------------------------------------
__global__ __launch_bounds__(256) void kv_gemm(
    const _Float16* __restrict__ yh,
    const _Float16* __restrict__ Wkt, const _Float16* __restrict__ Wvt,
    const float* __restrict__ bk, const float* __restrict__ bv,
    _Float16* __restrict__ kh, _Float16* __restrict__ vth)
{
    __shared__ _Float16 As[64 * 32];
    __shared__ _Float16 Bs[64 * 32];

    const int tid = threadIdx.x;
    const int wave = tid >> 6, lane = tid & 63;
    const int quad = lane >> 4, l16 = lane & 15;
    const int m0 = blockIdx.y * 64, n0 = blockIdx.x * 64;
    const bool isV = blockIdx.z != 0;
    const _Float16* Bt = isV ? Wvt : Wkt;
    const float* bias  = isV ? bv : bk;

    const int row = tid >> 2;        // 0..63
    const int kch = (tid & 3) * 8;   // k chunk (8 f16 = 16 B)

    floatx4 acc[4] = {};

    for (int k0 = 0; k0 < CROSS; k0 += 32) {
        lds_load16(&yh[(size_t)(m0 + row) * CROSS + k0 + kch], &As[wave * 512]);
        lds_load16(&Bt[(size_t)(n0 + row) * CROSS + k0 + kch], &Bs[wave * 512]);
        __syncthreads();
        half8 b = *(const half8*)&Bs[(wave * 16 + l16) * 32 + quad * 8];
        #pragma unroll
        for (int i = 0; i < 4; ++i) {
            half8 a = *(const half8*)&As[(i * 16 + l16) * 32 + quad * 8];
            acc[i] = __builtin_amdgcn_mfma_f32_16x16x32_f16(a, b, acc[i], 0, 0, 0);
        }
        __syncthreads();
    }

    const int n = n0 + wave * 16 + l16;     // 0..639
    const int h = n / HEAD, d = n % HEAD;
    const float bb = bias[n];
    #pragma unroll
    for (int i = 0; i < 4; ++i)
        #pragma unroll
        for (int r = 0; r < 4; ++r) {
            const int m = m0 + i * 16 + quad * 4 + r;
            if (m >= BATCH * SEQS) continue;
            const int b_ = m / SEQS, s = m % SEQS;
            const int bh = b_ * NH + h;
            const float v = acc[i][r] + bb;
            if (isV) vth[(size_t)bh * (HEAD * 80) + d * 80 + s] = (_Float16)v;
            else     kh [(size_t)bh * (SEQS * HEAD) + s * HEAD + d] = (_Float16)v;
        }
}

// ---------------------------------------------------------------------------
// MFMA attention v2: persistent K/V per block.
// Grid (16, 64): block = one (b,h) x 256 q-rows (4 tiles of 64).
// ---------------------------------------------------------------------------
__global__ __launch_bounds__(256, 4) void attn_mfma(
    const _Float16* __restrict__ qh,   // [M][EMBED], 1/sqrt(80) pre-folded
    const _Float16* __restrict__ kh,   // [64][77][80]
    const _Float16* __restrict__ vth,  // [64][80][80]
    _Float16* __restrict__ oh)         // [M][EMBED]
{
    constexpr int LS = 88;             // f16 LDS row stride (80 data + 8 pad)
    __shared__ _Float16 lds[(80 + 80 + 64) * LS + 8];
    _Float16* Ks = lds;                // [80][LS]  rows 77..79 zeroed
    _Float16* Vt = lds + 80 * LS;      // [80][LS]
    _Float16* Ps = lds + 160 * LS;     // [64][LS]

    const int tid = threadIdx.x;
    const int wave = tid >> 6, lane = tid & 63;
    const int quad = lane >> 4, l16 = lane & 15;
    const int bh = blockIdx.y;
    const int b = bh >> 3, h = bh & 7;
    const size_t row0 = (size_t)b * SEQT + (size_t)blockIdx.x * 256;
    const half8 hz = {};

    // Q base for this lane's A-fragment row (A row index = l16)
    const _Float16* qp = qh + (row0 + wave * 16 + l16) * EMBED + h * HEAD;

    // tile 0 Q fragments (overlap with staging below)
    half8 qa0 = *(const half8*)&qp[quad * 8];
    half8 qa1 = *(const half8*)&qp[32 + quad * 8];
    half8 qa2 = (quad < 2) ? *(const half8*)&qp[64 + quad * 8] : hz;

    // stage K (rows >= 77 and pad chunk zeroed)
    for (int idx = tid; idx < 80 * 11; idx += 256) {
        const int s = idx / 11, c = idx % 11;
        half8 v = hz;
        if (s < SEQS && c < 10)
            v = *(const half8*)&kh[(size_t)bh * (SEQS * HEAD) + s * HEAD + c * 8];
        *(half8*)&Ks[s * LS + c * 8] = v;
    }
    // stage V^T (pad chunk zeroed; cols s>=77 are zero in global)
    for (int idx = tid; idx < 80 * 11; idx += 256) {
        const int d = idx / 11, c = idx % 11;
        half8 v = hz;
        if (c < 10)
            v = *(const half8*)&vth[(size_t)bh * (HEAD * 80) + d * 80 + c * 8];
        *(half8*)&Vt[d * LS + c * 8] = v;
    }
    __syncthreads();

    for (int t = 0; t < 4; ++t) {
        // ---- QK^T ----
        floatx4 accs[5] = {};
        #pragma unroll
        for (int st = 0; st < 5; ++st) {
            const _Float16* kr = &Ks[(st * 16 + l16) * LS];
            half8 b0 = *(const half8*)&kr[quad * 8];
            half8 b1 = *(const half8*)&kr[32 + quad * 8];
            half8 b2 = *(const half8*)&kr[64 + quad * 8];
            accs[st] = __builtin_amdgcn_mfma_f32_16x16x32_f16(qa0, b0, accs[st], 0, 0, 0);
            accs[st] = __builtin_amdgcn_mfma_f32_16x16x32_f16(qa1, b1, accs[st], 0, 0, 0);
            accs[st] = __builtin_amdgcn_mfma_f32_16x16x32_f16(qa2, b2, accs[st], 0, 0, 0);
        }
        if (l16 >= 13) {
            accs[4][0] = -1e30f; accs[4][1] = -1e30f;
            accs[4][2] = -1e30f; accs[4][3] = -1e30f;
        }

        // ---- softmax (row = wave*16 + quad*4 + r, cols st*16 + l16) ----
        float recip[4];
        #pragma unroll
        for (int r = 0; r < 4; ++r) {
            float m = accs[0][r];
            #pragma unroll
            for (int st = 1; st < 5; ++st) m = fmaxf(m, accs[st][r]);
            m = fmaxf(m, __shfl_xor(m, 1));
            m = fmaxf(m, __shfl_xor(m, 2));
            m = fmaxf(m, __shfl_xor(m, 4));
            m = fmaxf(m, __shfl_xor(m, 8));
            float l = 0.f;
            const int row = wave * 16 + quad * 4 + r;
            #pragma unroll
            for (int st = 0; st < 5; ++st) {
                float e = __expf(accs[st][r] - m);
                l += e;
                Ps[row * LS + st * 16 + l16] = (_Float16)e;
            }
            l += __shfl_xor(l, 1);
            l += __shfl_xor(l, 2);
            l += __shfl_xor(l, 4);
            l += __shfl_xor(l, 8);
            recip[r] = 1.0f / l;
        }
        __syncthreads();   // Ps visible to all waves

        // prefetch next tile's Q fragments (hidden under PV)
        half8 qn0 = hz, qn1 = hz, qn2 = hz;
        if (t < 3) {
            const _Float16* qn = qp + (size_t)(t + 1) * 64 * EMBED;
            qn0 = *(const half8*)&qn[quad * 8];
            qn1 = *(const half8*)&qn[32 + quad * 8];
            if (quad < 2) qn2 = *(const half8*)&qn[64 + quad * 8];
        }

        // ---- load P fragments, release Ps ----
        const _Float16* pr = &Ps[(wave * 16 + l16) * LS];
        half8 pa0 = *(const half8*)&pr[quad * 8];
        half8 pa1 = *(const half8*)&pr[32 + quad * 8];
        half8 pa2 = (quad < 2) ? *(const half8*)&pr[64 + quad * 8] : hz;
        __syncthreads();   // Ps consumed; next iter may overwrite

        // ---- P @ V^T ----
        floatx4 acco[5] = {};
        #pragma unroll
        for (int dt = 0; dt < 5; ++dt) {
            const _Float16* vr = &Vt[(dt * 16 + l16) * LS];
            half8 b0 = *(const half8*)&vr[quad * 8];
            half8 b1 = *(const half8*)&vr[32 + quad * 8];
            half8 b2 = *(const half8*)&vr[64 + quad * 8];
            acco[dt] = __builtin_amdgcn_mfma_f32_16x16x32_f16(pa0, b0, acco[dt], 0, 0, 0);
            acco[dt] = __builtin_amdgcn_mfma_f32_16x16x32_f16(pa1, b1, acco[dt], 0, 0, 0);
            acco[dt] = __builtin_amdgcn_mfma_f32_16x16x32_f16(pa2, b2, acco[dt], 0, 0, 0);
        }

        // ---- store O ----
        #pragma unroll
        for (int r = 0; r < 4; ++r) {
            const size_t grow = row0 + t * 64 + wave * 16 + quad * 4 + r;
            #pragma unroll
            for (int dt = 0; dt < 5; ++dt)
                oh[grow * EMBED + h * HEAD + dt * 16 + l16] =
                    (_Float16)(acco[dt][r] * recip[r]);
        }

        qa0 = qn0; qa1 = qn1; qa2 = qn2;
    }
}

// ---------------------------------------------------------------------------
extern "C" void kernel_launch(void* const* d_in, const int* in_sizes, int n_in,
                              void* d_out, int out_size, void* d_ws, size_t ws_size,
                              hipStream_t stream)
{
    const float* x  = (const float*)d_in[0];
    const float* y  = (const float*)d_in[1];
    const float* Wq = (const float*)d_in[2];
    const float* bq = (const float*)d_in[3];
    const float* Wk = (const float*)d_in[4];
    const float* bk = (const float*)d_in[5];
    const float* Wv = (const float*)d_in[6];
    const float* bv = (const float*)d_in[7];
    const float* Wo = (const float*)d_in[8];
    const float* bo = (const float*)d_in[9];
    float* out = (float*)d_out;

    const size_t ME = (size_t)MROWS * EMBED;
    _Float16* qh  = (_Float16*)d_ws;                          // [M][640]
    _Float16* ah  = qh + ME;                                  // [M][640]
    _Float16* kh  = ah + ME;                                  // [64][77][80]
    _Float16* vth = kh  + (size_t)BATCH * NH * SEQS * HEAD;   // [64][80][80]
    _Float16* wqt = vth + (size_t)BATCH * NH * HEAD * 80;     // [640][640]
    _Float16* wot = wqt + (size_t)EMBED * EMBED;              // [640][640]
    _Float16* yh  = wot + (size_t)EMBED * EMBED;              // [640][768]
    _Float16* wkt = yh  + (size_t)640 * CROSS;                // [640][768]
    _Float16* wvt = wkt + (size_t)EMBED * CROSS;              // [640][768]

    // prep (2 launches)
    transpose_all<<<dim3(EMBED / 32, CROSS / 32, 4), dim3(32, 8), 0, stream>>>(
        Wq, Wo, Wk, Wv, wqt, wot, wkt, wvt);
    cvt_y_zero<<<dim3(440), 256, 0, stream>>>(y, yh, vth);

    // 1) Q = (x @ Wq + bq) * 1/sqrt(80), fused fp32->f16 cast of x
    gemm_q<<<dim3(EMBED / 128, MROWS / 128), 256, 0, stream>>>(x, wqt, bq, qh);
    // 2) K,V projections via MFMA -> attention layouts
    kv_gemm<<<dim3(EMBED / 64, 640 / 64, 2), 256, 0, stream>>>(
        yh, wkt, wvt, bk, bv, kh, vth);
    // 3) MFMA attention: persistent K/V, 256 q-rows per block
    attn_mfma<<<dim3(SEQT / 256, BATCH * NH), 256, 0, stream>>>(qh, kh, vth, ah);
    // 4) out = attn_out @ Wo + bo (fp32 out)
    gemm_f16<<<dim3(EMBED / 128, MROWS / 128), 256, 0, stream>>>(
        ah, wot, bo, out, MROWS, EMBED, EMBED);
}

// Round 5
// 294.325 us; speedup vs baseline: 1.0635x; 1.0635x over previous
//
#include <hip/hip_runtime.h>
#include <hip/hip_bf16.h>
#include <hip/hip_fp16.h>

#define EMBED 640
#define CROSS 768
#define NH 8
#define HEAD 80
#define BATCH 8
#define SEQT 4096
#define SEQS 77
#define MROWS (BATCH * SEQT)

typedef _Float16 half8 __attribute__((ext_vector_type(8)));
typedef float floatx4 __attribute__((ext_vector_type(4)));

__device__ __forceinline__ void lds_load16(const void* g, void* l) {
    __builtin_amdgcn_global_load_lds(
        (const __attribute__((address_space(1))) void*)g,
        (__attribute__((address_space(3))) void*)l, 16, 0, 0);
}

// ---------------------------------------------------------------------------
// fp32 -> f16 cast, 8 elems/thread (exact grids used).
// ---------------------------------------------------------------------------
__global__ __launch_bounds__(256) void cvt_f32_f16(
    const float* __restrict__ in, _Float16* __restrict__ out)
{
    size_t i = ((size_t)blockIdx.x * 256 + threadIdx.x) * 8;
    float4 a = *(const float4*)&in[i];
    float4 b = *(const float4*)&in[i + 4];
    half8 h;
    h[0] = (_Float16)a.x; h[1] = (_Float16)a.y;
    h[2] = (_Float16)a.z; h[3] = (_Float16)a.w;
    h[4] = (_Float16)b.x; h[5] = (_Float16)b.y;
    h[6] = (_Float16)b.z; h[7] = (_Float16)b.w;
    *(half8*)&out[i] = h;
}

// ---------------------------------------------------------------------------
// All four weight transposes in one launch. z: 0=Wq 1=Wo 2=Wk 3=Wv.
// W [K,N] fp32 -> Wt [N,K] f16 (tiled 32x32).
// ---------------------------------------------------------------------------
__global__ __launch_bounds__(256) void transpose_all(
    const float* __restrict__ Wq, const float* __restrict__ Wo,
    const float* __restrict__ Wk, const float* __restrict__ Wv,
    _Float16* __restrict__ wqt, _Float16* __restrict__ wot,
    _Float16* __restrict__ wkt, _Float16* __restrict__ wvt)
{
    __shared__ float t[32][33];
    const int z = blockIdx.z;
    const float* W;  _Float16* Wt;  int K;
    if      (z == 0) { W = Wq; Wt = wqt; K = EMBED; }
    else if (z == 1) { W = Wo; Wt = wot; K = EMBED; }
    else if (z == 2) { W = Wk; Wt = wkt; K = CROSS; }
    else             { W = Wv; Wt = wvt; K = CROSS; }
    const int N = EMBED;
    const int k0 = blockIdx.y * 32, n0 = blockIdx.x * 32;
    if (k0 >= K) return;
    for (int r = threadIdx.y; r < 32; r += 8)
        t[r][threadIdx.x] = W[(size_t)(k0 + r) * N + n0 + threadIdx.x];
    __syncthreads();
    for (int r = threadIdx.y; r < 32; r += 8)
        Wt[(size_t)(n0 + r) * K + k0 + threadIdx.x] = (_Float16)t[threadIdx.x][r];
}

// ---------------------------------------------------------------------------
// y [616*768] fp32 -> yh [640][768] f16 (rows 616+ zeroed)  AND  vth zero.
// Grid exactly 440*256 threads = 61440 (yh) + 51200 (vth) 8-elem slots.
// ---------------------------------------------------------------------------
__global__ __launch_bounds__(256) void cvt_y_zero(
    const float* __restrict__ y, _Float16* __restrict__ yh,
    _Float16* __restrict__ vth)
{
    const size_t i = (size_t)blockIdx.x * 256 + threadIdx.x;
    if (i < (size_t)640 * CROSS / 8) {
        const size_t e = i * 8;
        half8 h = {};
        if (e < (size_t)BATCH * SEQS * CROSS) {
            float4 a = *(const float4*)&y[e];
            float4 b = *(const float4*)&y[e + 4];
            h[0] = (_Float16)a.x; h[1] = (_Float16)a.y;
            h[2] = (_Float16)a.z; h[3] = (_Float16)a.w;
            h[4] = (_Float16)b.x; h[5] = (_Float16)b.y;
            h[6] = (_Float16)b.z; h[7] = (_Float16)b.w;
        }
        *(half8*)&yh[e] = h;
    } else {
        const size_t j = (i - (size_t)640 * CROSS / 8) * 8;
        *(half8*)&vth[j] = (half8){};
    }
}

// ---------------------------------------------------------------------------
// f16 MFMA GEMM: C = A[M,K] @ Bt[N,K]^T + bias, then *scale.
// v5 structure: ONE barrier per K-step; 3-buffer LDS; counted vmcnt(4) in
// steady state (the next stage-tile stays in flight across the barrier).
// stage(t+2) issued right after the barrier overwrites buf (t-1)%3, whose
// ds_reads all retired before MFMA(t-1) and hence before this barrier.
// XCD-aware remap + chunk XOR swizzle (bank conflicts = 0).
// HALF_OUT: f16 out with scale folded (Q path); else fp32 out.
// ---------------------------------------------------------------------------
template <bool HALF_OUT>
__global__ __launch_bounds__(256) void gemm_f16(
    const _Float16* __restrict__ A,   // [M,K] f16
    const _Float16* __restrict__ Bt,  // [N,K] f16
    const float* __restrict__ bias,
    void* __restrict__ Cout, int M, int N, int K, float scale)
{
    __shared__ _Float16 As[3][128 * 32];
    __shared__ _Float16 Bs[3][128 * 32];

    const int tid  = threadIdx.x;
    const int wave = tid >> 6;
    const int lane = tid & 63;
    const int quad = lane >> 4;
    const int l16  = lane & 15;

    // XCD-aware remap: the gridDim.x n-tiles of one m-panel -> same XCD.
    const int l   = blockIdx.y * gridDim.x + blockIdx.x;
    const int inner = l >> 3;
    const int p   = (l & 7) + 8 * (inner / gridDim.x);
    const int nt  = inner % gridDim.x;
    const int m0 = p * 128, n0 = nt * 128;
    const int wm = (wave >> 1) * 64, wn = (wave & 1) * 64;

    const int row = tid >> 2;
    const int kch = ((tid & 3) ^ ((row >> 1) & 3)) * 8;   // pre-swizzled src
    const int cq  = (quad ^ ((l16 >> 1) & 3)) * 8;        // swizzled read

    const _Float16* pa0 = &A [(size_t)(m0 + row)      * K + kch];
    const _Float16* pa1 = &A [(size_t)(m0 + 64 + row) * K + kch];
    const _Float16* pb0 = &Bt[(size_t)(n0 + row)      * K + kch];
    const _Float16* pb1 = &Bt[(size_t)(n0 + 64 + row) * K + kch];

    const int NT = K / 32;   // 20

    auto stage = [&](int t) {
        const int bf = t % 3;
        const int off = t * 32;
        lds_load16(pa0 + off, &As[bf][wave * 512]);
        lds_load16(pa1 + off, &As[bf][2048 + wave * 512]);
        lds_load16(pb0 + off, &Bs[bf][wave * 512]);
        lds_load16(pb1 + off, &Bs[bf][2048 + wave * 512]);
    };
    stage(0); stage(1);      // 8 loads in flight

    floatx4 acc[4][4] = {};

    for (int t = 0; t < NT; ++t) {
        // my stage(t) landed; leave stage(t+1) in flight
        if (t < NT - 1) asm volatile("s_waitcnt vmcnt(4)" ::: "memory");
        else            asm volatile("s_waitcnt vmcnt(0)" ::: "memory");
        __builtin_amdgcn_s_barrier();   // all waves' stage(t) visible
        if (t + 2 < NT) stage(t + 2);   // overwrites buf (t-1)%3 (free)

        const _Float16* as = As[t % 3];
        const _Float16* bs = Bs[t % 3];
        half8 a[4], b[4];
        #pragma unroll
        for (int i = 0; i < 4; ++i)
            a[i] = *(const half8*)&as[(wm + i * 16 + l16) * 32 + cq];
        #pragma unroll
        for (int j = 0; j < 4; ++j)
            b[j] = *(const half8*)&bs[(wn + j * 16 + l16) * 32 + cq];
        #pragma unroll
        for (int i = 0; i < 4; ++i)
            #pragma unroll
            for (int j = 0; j < 4; ++j)
                acc[i][j] = __builtin_amdgcn_mfma_f32_16x16x32_f16(
                    a[i], b[j], acc[i][j], 0, 0, 0);
    }

    float bcol[4];
    #pragma unroll
    for (int j = 0; j < 4; ++j) bcol[j] = bias[n0 + wn + j * 16 + l16];
    #pragma unroll
    for (int i = 0; i < 4; ++i)
        #pragma unroll
        for (int r = 0; r < 4; ++r) {
            const int m = m0 + wm + i * 16 + quad * 4 + r;
            #pragma unroll
            for (int j = 0; j < 4; ++j) {
                float v = (acc[i][j][r] + bcol[j]) * scale;
                const size_t off = (size_t)m * N + n0 + wn + j * 16 + l16;
                if (HALF_OUT) ((_Float16*)Cout)[off] = (_Float16)v;
                else          ((float*)Cout)[off] = v;
            }
        }
}

// ---------------------------------------------------------------------------
// K/V projection via MFMA. 64x64 tiles, 4 waves (wave w = cols w*16..w*16+15).
// A = yh [640][768] f16 (rows 616+ zero), B = Wkt/Wvt [640][768] f16.
// Epilogue scatters f16 into attention layouts:
//   kh [bh][s(77)][d(80)], vth[bh][d(80)][s(80, pads pre-zeroed)]
// ---------------------------------------------------------------------------
__global__ __launch_bounds__(256) void kv_gemm(
    const _Float16* __restrict__ yh,
    const _Float16* __restrict__ Wkt, const _Float16* __restrict__ Wvt,
    const float* __restrict__ bk, const float* __restrict__ bv,
    _Float16* __restrict__ kh, _Float16* __restrict__ vth)
{
    __shared__ _Float16 As[64 * 32];
    __shared__ _Float16 Bs[64 * 32];

    const int tid = threadIdx.x;
    const int wave = tid >> 6, lane = tid & 63;
    const int quad = lane >> 4, l16 = lane & 15;
    const int m0 = blockIdx.y * 64, n0 = blockIdx.x * 64;
    const bool isV = blockIdx.z != 0;
    const _Float16* Bt = isV ? Wvt : Wkt;
    const float* bias  = isV ? bv : bk;

    const int row = tid >> 2;        // 0..63
    const int kch = (tid & 3) * 8;   // k chunk (8 f16 = 16 B)

    floatx4 acc[4] = {};

    for (int k0 = 0; k0 < CROSS; k0 += 32) {
        lds_load16(&yh[(size_t)(m0 + row) * CROSS + k0 + kch], &As[wave * 512]);
        lds_load16(&Bt[(size_t)(n0 + row) * CROSS + k0 + kch], &Bs[wave * 512]);
        __syncthreads();
        half8 b = *(const half8*)&Bs[(wave * 16 + l16) * 32 + quad * 8];
        #pragma unroll
        for (int i = 0; i < 4; ++i) {
            half8 a = *(const half8*)&As[(i * 16 + l16) * 32 + quad * 8];
            acc[i] = __builtin_amdgcn_mfma_f32_16x16x32_f16(a, b, acc[i], 0, 0, 0);
        }
        __syncthreads();
    }

    const int n = n0 + wave * 16 + l16;     // 0..639
    const int h = n / HEAD, d = n % HEAD;
    const float bb = bias[n];
    #pragma unroll
    for (int i = 0; i < 4; ++i)
        #pragma unroll
        for (int r = 0; r < 4; ++r) {
            const int m = m0 + i * 16 + quad * 4 + r;
            if (m >= BATCH * SEQS) continue;
            const int b_ = m / SEQS, s = m % SEQS;
            const int bh = b_ * NH + h;
            const float v = acc[i][r] + bb;
            if (isV) vth[(size_t)bh * (HEAD * 80) + d * 80 + s] = (_Float16)v;
            else     kh [(size_t)bh * (SEQS * HEAD) + s * HEAD + d] = (_Float16)v;
        }
}

// ---------------------------------------------------------------------------
// MFMA attention v2: persistent K/V per block.
// Grid (16, 64): block = one (b,h) x 256 q-rows (4 tiles of 64).
// ---------------------------------------------------------------------------
__global__ __launch_bounds__(256, 4) void attn_mfma(
    const _Float16* __restrict__ qh,   // [M][EMBED], 1/sqrt(80) pre-folded
    const _Float16* __restrict__ kh,   // [64][77][80]
    const _Float16* __restrict__ vth,  // [64][80][80]
    _Float16* __restrict__ oh)         // [M][EMBED]
{
    constexpr int LS = 88;             // f16 LDS row stride (80 data + 8 pad)
    __shared__ _Float16 lds[(80 + 80 + 64) * LS + 8];
    _Float16* Ks = lds;                // [80][LS]  rows 77..79 zeroed
    _Float16* Vt = lds + 80 * LS;      // [80][LS]
    _Float16* Ps = lds + 160 * LS;     // [64][LS]

    const int tid = threadIdx.x;
    const int wave = tid >> 6, lane = tid & 63;
    const int quad = lane >> 4, l16 = lane & 15;
    const int bh = blockIdx.y;
    const int b = bh >> 3, h = bh & 7;
    const size_t row0 = (size_t)b * SEQT + (size_t)blockIdx.x * 256;
    const half8 hz = {};

    // Q base for this lane's A-fragment row (A row index = l16)
    const _Float16* qp = qh + (row0 + wave * 16 + l16) * EMBED + h * HEAD;

    // tile 0 Q fragments (overlap with staging below)
    half8 qa0 = *(const half8*)&qp[quad * 8];
    half8 qa1 = *(const half8*)&qp[32 + quad * 8];
    half8 qa2 = (quad < 2) ? *(const half8*)&qp[64 + quad * 8] : hz;

    // stage K (rows >= 77 and pad chunk zeroed)
    for (int idx = tid; idx < 80 * 11; idx += 256) {
        const int s = idx / 11, c = idx % 11;
        half8 v = hz;
        if (s < SEQS && c < 10)
            v = *(const half8*)&kh[(size_t)bh * (SEQS * HEAD) + s * HEAD + c * 8];
        *(half8*)&Ks[s * LS + c * 8] = v;
    }
    // stage V^T (pad chunk zeroed; cols s>=77 are zero in global)
    for (int idx = tid; idx < 80 * 11; idx += 256) {
        const int d = idx / 11, c = idx % 11;
        half8 v = hz;
        if (c < 10)
            v = *(const half8*)&vth[(size_t)bh * (HEAD * 80) + d * 80 + c * 8];
        *(half8*)&Vt[d * LS + c * 8] = v;
    }
    __syncthreads();

    for (int t = 0; t < 4; ++t) {
        // ---- QK^T ----
        floatx4 accs[5] = {};
        #pragma unroll
        for (int st = 0; st < 5; ++st) {
            const _Float16* kr = &Ks[(st * 16 + l16) * LS];
            half8 b0 = *(const half8*)&kr[quad * 8];
            half8 b1 = *(const half8*)&kr[32 + quad * 8];
            half8 b2 = *(const half8*)&kr[64 + quad * 8];
            accs[st] = __builtin_amdgcn_mfma_f32_16x16x32_f16(qa0, b0, accs[st], 0, 0, 0);
            accs[st] = __builtin_amdgcn_mfma_f32_16x16x32_f16(qa1, b1, accs[st], 0, 0, 0);
            accs[st] = __builtin_amdgcn_mfma_f32_16x16x32_f16(qa2, b2, accs[st], 0, 0, 0);
        }
        if (l16 >= 13) {
            accs[4][0] = -1e30f; accs[4][1] = -1e30f;
            accs[4][2] = -1e30f; accs[4][3] = -1e30f;
        }

        // ---- softmax (row = wave*16 + quad*4 + r, cols st*16 + l16) ----
        float recip[4];
        #pragma unroll
        for (int r = 0; r < 4; ++r) {
            float m = accs[0][r];
            #pragma unroll
            for (int st = 1; st < 5; ++st) m = fmaxf(m, accs[st][r]);
            m = fmaxf(m, __shfl_xor(m, 1));
            m = fmaxf(m, __shfl_xor(m, 2));
            m = fmaxf(m, __shfl_xor(m, 4));
            m = fmaxf(m, __shfl_xor(m, 8));
            float l = 0.f;
            const int row = wave * 16 + quad * 4 + r;
            #pragma unroll
            for (int st = 0; st < 5; ++st) {
                float e = __expf(accs[st][r] - m);
                l += e;
                Ps[row * LS + st * 16 + l16] = (_Float16)e;
            }
            l += __shfl_xor(l, 1);
            l += __shfl_xor(l, 2);
            l += __shfl_xor(l, 4);
            l += __shfl_xor(l, 8);
            recip[r] = 1.0f / l;
        }
        __syncthreads();   // Ps visible to all waves

        // prefetch next tile's Q fragments (hidden under PV)
        half8 qn0 = hz, qn1 = hz, qn2 = hz;
        if (t < 3) {
            const _Float16* qn = qp + (size_t)(t + 1) * 64 * EMBED;
            qn0 = *(const half8*)&qn[quad * 8];
            qn1 = *(const half8*)&qn[32 + quad * 8];
            if (quad < 2) qn2 = *(const half8*)&qn[64 + quad * 8];
        }

        // ---- load P fragments, release Ps ----
        const _Float16* pr = &Ps[(wave * 16 + l16) * LS];
        half8 pa0 = *(const half8*)&pr[quad * 8];
        half8 pa1 = *(const half8*)&pr[32 + quad * 8];
        half8 pa2 = (quad < 2) ? *(const half8*)&pr[64 + quad * 8] : hz;
        __syncthreads();   // Ps consumed; next iter may overwrite

        // ---- P @ V^T ----
        floatx4 acco[5] = {};
        #pragma unroll
        for (int dt = 0; dt < 5; ++dt) {
            const _Float16* vr = &Vt[(dt * 16 + l16) * LS];
            half8 b0 = *(const half8*)&vr[quad * 8];
            half8 b1 = *(const half8*)&vr[32 + quad * 8];
            half8 b2 = *(const half8*)&vr[64 + quad * 8];
            acco[dt] = __builtin_amdgcn_mfma_f32_16x16x32_f16(pa0, b0, acco[dt], 0, 0, 0);
            acco[dt] = __builtin_amdgcn_mfma_f32_16x16x32_f16(pa1, b1, acco[dt], 0, 0, 0);
            acco[dt] = __builtin_amdgcn_mfma_f32_16x16x32_f16(pa2, b2, acco[dt], 0, 0, 0);
        }

        // ---- store O ----
        #pragma unroll
        for (int r = 0; r < 4; ++r) {
            const size_t grow = row0 + t * 64 + wave * 16 + quad * 4 + r;
            #pragma unroll
            for (int dt = 0; dt < 5; ++dt)
                oh[grow * EMBED + h * HEAD + dt * 16 + l16] =
                    (_Float16)(acco[dt][r] * recip[r]);
        }

        qa0 = qn0; qa1 = qn1; qa2 = qn2;
    }
}

// ---------------------------------------------------------------------------
extern "C" void kernel_launch(void* const* d_in, const int* in_sizes, int n_in,
                              void* d_out, int out_size, void* d_ws, size_t ws_size,
                              hipStream_t stream)
{
    const float* x  = (const float*)d_in[0];
    const float* y  = (const float*)d_in[1];
    const float* Wq = (const float*)d_in[2];
    const float* bq = (const float*)d_in[3];
    const float* Wk = (const float*)d_in[4];
    const float* bk = (const float*)d_in[5];
    const float* Wv = (const float*)d_in[6];
    const float* bv = (const float*)d_in[7];
    const float* Wo = (const float*)d_in[8];
    const float* bo = (const float*)d_in[9];
    float* out = (float*)d_out;

    const size_t ME = (size_t)MROWS * EMBED;
    _Float16* xh  = (_Float16*)d_ws;                          // [M][640]
    _Float16* qh  = xh + ME;                                  // [M][640]
    _Float16* ah  = qh + ME;                                  // [M][640]
    _Float16* kh  = ah + ME;                                  // [64][77][80]
    _Float16* vth = kh  + (size_t)BATCH * NH * SEQS * HEAD;   // [64][80][80]
    _Float16* wqt = vth + (size_t)BATCH * NH * HEAD * 80;     // [640][640]
    _Float16* wot = wqt + (size_t)EMBED * EMBED;              // [640][640]
    _Float16* yh  = wot + (size_t)EMBED * EMBED;              // [640][768]
    _Float16* wkt = yh  + (size_t)640 * CROSS;                // [640][768]
    _Float16* wvt = wkt + (size_t)EMBED * CROSS;              // [640][768]

    // prep (3 launches)
    transpose_all<<<dim3(EMBED / 32, CROSS / 32, 4), dim3(32, 8), 0, stream>>>(
        Wq, Wo, Wk, Wv, wqt, wot, wkt, wvt);
    cvt_y_zero<<<dim3(440), 256, 0, stream>>>(y, yh, vth);
    cvt_f32_f16<<<dim3(ME / (256 * 8)), 256, 0, stream>>>(x, xh);

    // 1) Q = (x @ Wq + bq) * 1/sqrt(80), f16 out (v5 gemm)
    gemm_f16<true><<<dim3(EMBED / 128, MROWS / 128), 256, 0, stream>>>(
        xh, wqt, bq, qh, MROWS, EMBED, EMBED, 0.11180339887498949f);
    // 2) K,V projections via MFMA -> attention layouts
    kv_gemm<<<dim3(EMBED / 64, 640 / 64, 2), 256, 0, stream>>>(
        yh, wkt, wvt, bk, bv, kh, vth);
    // 3) MFMA attention: persistent K/V, 256 q-rows per block
    attn_mfma<<<dim3(SEQT / 256, BATCH * NH), 256, 0, stream>>>(qh, kh, vth, ah);
    // 4) out = attn_out @ Wo + bo (fp32 out, v5 gemm)
    gemm_f16<false><<<dim3(EMBED / 128, MROWS / 128), 256, 0, stream>>>(
        ah, wot, bo, out, MROWS, EMBED, EMBED, 1.0f);
}

// Round 6
// 288.184 us; speedup vs baseline: 1.0862x; 1.0213x over previous
//
#include <hip/hip_runtime.h>
#include <hip/hip_bf16.h>
#include <hip/hip_fp16.h>

#define EMBED 640
#define CROSS 768
#define NH 8
#define HEAD 80
#define BATCH 8
#define SEQT 4096
#define SEQS 77
#define MROWS (BATCH * SEQT)

typedef _Float16 half8 __attribute__((ext_vector_type(8)));
typedef float floatx4 __attribute__((ext_vector_type(4)));

__device__ __forceinline__ void lds_load16(const void* g, void* l) {
    __builtin_amdgcn_global_load_lds(
        (const __attribute__((address_space(1))) void*)g,
        (__attribute__((address_space(3))) void*)l, 16, 0, 0);
}

// ---------------------------------------------------------------------------
// fp32 -> f16 cast, 8 elems/thread (exact grids used).
// ---------------------------------------------------------------------------
__global__ __launch_bounds__(256) void cvt_f32_f16(
    const float* __restrict__ in, _Float16* __restrict__ out)
{
    size_t i = ((size_t)blockIdx.x * 256 + threadIdx.x) * 8;
    float4 a = *(const float4*)&in[i];
    float4 b = *(const float4*)&in[i + 4];
    half8 h;
    h[0] = (_Float16)a.x; h[1] = (_Float16)a.y;
    h[2] = (_Float16)a.z; h[3] = (_Float16)a.w;
    h[4] = (_Float16)b.x; h[5] = (_Float16)b.y;
    h[6] = (_Float16)b.z; h[7] = (_Float16)b.w;
    *(half8*)&out[i] = h;
}

// ---------------------------------------------------------------------------
// All four weight transposes in one launch. z: 0=Wq 1=Wo 2=Wk 3=Wv.
// W [K,N] fp32 -> Wt [N,K] f16 (tiled 32x32).
// ---------------------------------------------------------------------------
__global__ __launch_bounds__(256) void transpose_all(
    const float* __restrict__ Wq, const float* __restrict__ Wo,
    const float* __restrict__ Wk, const float* __restrict__ Wv,
    _Float16* __restrict__ wqt, _Float16* __restrict__ wot,
    _Float16* __restrict__ wkt, _Float16* __restrict__ wvt)
{
    __shared__ float t[32][33];
    const int z = blockIdx.z;
    const float* W;  _Float16* Wt;  int K;
    if      (z == 0) { W = Wq; Wt = wqt; K = EMBED; }
    else if (z == 1) { W = Wo; Wt = wot; K = EMBED; }
    else if (z == 2) { W = Wk; Wt = wkt; K = CROSS; }
    else             { W = Wv; Wt = wvt; K = CROSS; }
    const int N = EMBED;
    const int k0 = blockIdx.y * 32, n0 = blockIdx.x * 32;
    if (k0 >= K) return;
    for (int r = threadIdx.y; r < 32; r += 8)
        t[r][threadIdx.x] = W[(size_t)(k0 + r) * N + n0 + threadIdx.x];
    __syncthreads();
    for (int r = threadIdx.y; r < 32; r += 8)
        Wt[(size_t)(n0 + r) * K + k0 + threadIdx.x] = (_Float16)t[threadIdx.x][r];
}

// ---------------------------------------------------------------------------
// y [616*768] fp32 -> yh [640][768] f16 (rows 616+ zeroed)  AND  vth zero.
// ---------------------------------------------------------------------------
__global__ __launch_bounds__(256) void cvt_y_zero(
    const float* __restrict__ y, _Float16* __restrict__ yh,
    _Float16* __restrict__ vth)
{
    const size_t i = (size_t)blockIdx.x * 256 + threadIdx.x;
    if (i < (size_t)640 * CROSS / 8) {
        const size_t e = i * 8;
        half8 h = {};
        if (e < (size_t)BATCH * SEQS * CROSS) {
            float4 a = *(const float4*)&y[e];
            float4 b = *(const float4*)&y[e + 4];
            h[0] = (_Float16)a.x; h[1] = (_Float16)a.y;
            h[2] = (_Float16)a.z; h[3] = (_Float16)a.w;
            h[4] = (_Float16)b.x; h[5] = (_Float16)b.y;
            h[6] = (_Float16)b.z; h[7] = (_Float16)b.w;
        }
        *(half8*)&yh[e] = h;
    } else {
        const size_t j = (i - (size_t)640 * CROSS / 8) * 8;
        *(half8*)&vth[j] = (half8){};
    }
}

// ---------------------------------------------------------------------------
// f16 MFMA GEMM v6: C = A[M,K] @ Bt[N,K]^T + bias, then *scale.
// BK=64 K-tiles, double-buffered (64 KB LDS -> 2 blocks/CU), stage-first +
// counted vmcnt(8): tile t+1's 8 global_load_lds stay in flight across the
// barrier; 32 MFMA between barrier events (2x the old BK=32).
// LDS row = 128 B -> 8-slot XOR swizzle (slot = chunk ^ (row&7)), both-sides:
// pre-swizzled global source, lane-linear gload_lds dest, swizzled read.
// XCD-aware remap unchanged. Accumulation order identical to v5.
// ---------------------------------------------------------------------------
template <bool HALF_OUT>
__global__ __launch_bounds__(256) void gemm_f16(
    const _Float16* __restrict__ A,   // [M,K] f16
    const _Float16* __restrict__ Bt,  // [N,K] f16
    const float* __restrict__ bias,
    void* __restrict__ Cout, int M, int N, int K, float scale)
{
    __shared__ _Float16 As[2][128 * 64];
    __shared__ _Float16 Bs[2][128 * 64];

    const int tid  = threadIdx.x;
    const int wave = tid >> 6;
    const int lane = tid & 63;
    const int quad = lane >> 4;
    const int l16  = lane & 15;

    // XCD-aware remap: the gridDim.x n-tiles of one m-panel -> same XCD.
    const int l   = blockIdx.y * gridDim.x + blockIdx.x;
    const int inner = l >> 3;
    const int p   = (l & 7) + 8 * (inner / gridDim.x);
    const int nt  = inner % gridDim.x;
    const int m0 = p * 128, n0 = nt * 128;
    const int wm = (wave >> 1) * 64, wn = (wave & 1) * 64;

    // staging map: instruction q of wave w fills LDS rows (w*4+q)*8..+8
    // (1 KB, lane-linear). lane l -> row sub = l>>3, slot = l&7, and the
    // global chunk for slot s at row r is s ^ (r&7) = (l&7) ^ (l>>3).
    const int srow = wave * 32 + (lane >> 3);          // + q*8
    const int sch  = ((lane & 7) ^ (lane >> 3)) * 8;   // pre-swizzled chunk
    const _Float16* gA[4];
    const _Float16* gB[4];
    #pragma unroll
    for (int q = 0; q < 4; ++q) {
        gA[q] = &A [(size_t)(m0 + srow + q * 8) * K + sch];
        gB[q] = &Bt[(size_t)(n0 + srow + q * 8) * K + sch];
    }

    const int NT = K / 64;   // 10

    auto stage = [&](int t, int bf) {
        const size_t off = (size_t)t * 64;
        #pragma unroll
        for (int q = 0; q < 4; ++q) {
            lds_load16(gA[q] + off, &As[bf][(wave * 4 + q) * 512]);
            lds_load16(gB[q] + off, &Bs[bf][(wave * 4 + q) * 512]);
        }
    };
    stage(0, 0);             // 8 loads in flight

    floatx4 acc[4][4] = {};

    for (int t = 0; t < NT; ++t) {
        const int bf = t & 1;
        if (t + 1 < NT) {
            stage(t + 1, bf ^ 1);                       // 16 outstanding
            asm volatile("s_waitcnt vmcnt(8)" ::: "memory");  // tile t landed
        } else {
            asm volatile("s_waitcnt vmcnt(0)" ::: "memory");
        }
        __builtin_amdgcn_s_barrier();       // all waves' tile t visible
        __builtin_amdgcn_sched_barrier(0);

        const _Float16* as = As[bf];
        const _Float16* bs = Bs[bf];
        __builtin_amdgcn_s_setprio(1);
        #pragma unroll
        for (int k = 0; k < 2; ++k) {
            half8 a[4], b[4];
            #pragma unroll
            for (int i = 0; i < 4; ++i)
                a[i] = *(const half8*)&as[(wm + i * 16 + l16) * 64 +
                                          (((k * 4 + quad) ^ (l16 & 7)) * 8)];
            #pragma unroll
            for (int j = 0; j < 4; ++j)
                b[j] = *(const half8*)&bs[(wn + j * 16 + l16) * 64 +
                                          (((k * 4 + quad) ^ (l16 & 7)) * 8)];
            #pragma unroll
            for (int i = 0; i < 4; ++i)
                #pragma unroll
                for (int j = 0; j < 4; ++j)
                    acc[i][j] = __builtin_amdgcn_mfma_f32_16x16x32_f16(
                        a[i], b[j], acc[i][j], 0, 0, 0);
        }
        __builtin_amdgcn_s_setprio(0);

        asm volatile("s_waitcnt lgkmcnt(0)" ::: "memory");
        __builtin_amdgcn_sched_barrier(0);
        __builtin_amdgcn_s_barrier();       // tile-t buffer free to restage
    }

    float bcol[4];
    #pragma unroll
    for (int j = 0; j < 4; ++j) bcol[j] = bias[n0 + wn + j * 16 + l16];
    #pragma unroll
    for (int i = 0; i < 4; ++i)
        #pragma unroll
        for (int r = 0; r < 4; ++r) {
            const int m = m0 + wm + i * 16 + quad * 4 + r;
            #pragma unroll
            for (int j = 0; j < 4; ++j) {
                float v = (acc[i][j][r] + bcol[j]) * scale;
                const size_t off = (size_t)m * N + n0 + wn + j * 16 + l16;
                if (HALF_OUT) ((_Float16*)Cout)[off] = (_Float16)v;
                else          ((float*)Cout)[off] = v;
            }
        }
}

// ---------------------------------------------------------------------------
// K/V projection via MFMA. 64x64 tiles, 4 waves (wave w = cols w*16..w*16+15).
// A = yh [640][768] f16 (rows 616+ zero), B = Wkt/Wvt [640][768] f16.
// Epilogue scatters f16 into attention layouts:
//   kh [bh][s(77)][d(80)], vth[bh][d(80)][s(80, pads pre-zeroed)]
// ---------------------------------------------------------------------------
__global__ __launch_bounds__(256) void kv_gemm(
    const _Float16* __restrict__ yh,
    const _Float16* __restrict__ Wkt, const _Float16* __restrict__ Wvt,
    const float* __restrict__ bk, const float* __restrict__ bv,
    _Float16* __restrict__ kh, _Float16* __restrict__ vth)
{
    __shared__ _Float16 As[64 * 32];
    __shared__ _Float16 Bs[64 * 32];

    const int tid = threadIdx.x;
    const int wave = tid >> 6, lane = tid & 63;
    const int quad = lane >> 4, l16 = lane & 15;
    const int m0 = blockIdx.y * 64, n0 = blockIdx.x * 64;
    const bool isV = blockIdx.z != 0;
    const _Float16* Bt = isV ? Wvt : Wkt;
    const float* bias  = isV ? bv : bk;

    const int row = tid >> 2;        // 0..63
    const int kch = (tid & 3) * 8;   // k chunk (8 f16 = 16 B)

    floatx4 acc[4] = {};

    for (int k0 = 0; k0 < CROSS; k0 += 32) {
        lds_load16(&yh[(size_t)(m0 + row) * CROSS + k0 + kch], &As[wave * 512]);
        lds_load16(&Bt[(size_t)(n0 + row) * CROSS + k0 + kch], &Bs[wave * 512]);
        __syncthreads();
        half8 b = *(const half8*)&Bs[(wave * 16 + l16) * 32 + quad * 8];
        #pragma unroll
        for (int i = 0; i < 4; ++i) {
            half8 a = *(const half8*)&As[(i * 16 + l16) * 32 + quad * 8];
            acc[i] = __builtin_amdgcn_mfma_f32_16x16x32_f16(a, b, acc[i], 0, 0, 0);
        }
        __syncthreads();
    }

    const int n = n0 + wave * 16 + l16;     // 0..639
    const int h = n / HEAD, d = n % HEAD;
    const float bb = bias[n];
    #pragma unroll
    for (int i = 0; i < 4; ++i)
        #pragma unroll
        for (int r = 0; r < 4; ++r) {
            const int m = m0 + i * 16 + quad * 4 + r;
            if (m >= BATCH * SEQS) continue;
            const int b_ = m / SEQS, s = m % SEQS;
            const int bh = b_ * NH + h;
            const float v = acc[i][r] + bb;
            if (isV) vth[(size_t)bh * (HEAD * 80) + d * 80 + s] = (_Float16)v;
            else     kh [(size_t)bh * (SEQS * HEAD) + s * HEAD + d] = (_Float16)v;
        }
}

// ---------------------------------------------------------------------------
// MFMA attention v2: persistent K/V per block.
// Grid (16, 64): block = one (b,h) x 256 q-rows (4 tiles of 64).
// ---------------------------------------------------------------------------
__global__ __launch_bounds__(256, 4) void attn_mfma(
    const _Float16* __restrict__ qh,   // [M][EMBED], 1/sqrt(80) pre-folded
    const _Float16* __restrict__ kh,   // [64][77][80]
    const _Float16* __restrict__ vth,  // [64][80][80]
    _Float16* __restrict__ oh)         // [M][EMBED]
{
    constexpr int LS = 88;             // f16 LDS row stride (80 data + 8 pad)
    __shared__ _Float16 lds[(80 + 80 + 64) * LS + 8];
    _Float16* Ks = lds;                // [80][LS]  rows 77..79 zeroed
    _Float16* Vt = lds + 80 * LS;      // [80][LS]
    _Float16* Ps = lds + 160 * LS;     // [64][LS]

    const int tid = threadIdx.x;
    const int wave = tid >> 6, lane = tid & 63;
    const int quad = lane >> 4, l16 = lane & 15;
    const int bh = blockIdx.y;
    const int b = bh >> 3, h = bh & 7;
    const size_t row0 = (size_t)b * SEQT + (size_t)blockIdx.x * 256;
    const half8 hz = {};

    // Q base for this lane's A-fragment row (A row index = l16)
    const _Float16* qp = qh + (row0 + wave * 16 + l16) * EMBED + h * HEAD;

    // tile 0 Q fragments (overlap with staging below)
    half8 qa0 = *(const half8*)&qp[quad * 8];
    half8 qa1 = *(const half8*)&qp[32 + quad * 8];
    half8 qa2 = (quad < 2) ? *(const half8*)&qp[64 + quad * 8] : hz;

    // stage K (rows >= 77 and pad chunk zeroed)
    for (int idx = tid; idx < 80 * 11; idx += 256) {
        const int s = idx / 11, c = idx % 11;
        half8 v = hz;
        if (s < SEQS && c < 10)
            v = *(const half8*)&kh[(size_t)bh * (SEQS * HEAD) + s * HEAD + c * 8];
        *(half8*)&Ks[s * LS + c * 8] = v;
    }
    // stage V^T (pad chunk zeroed; cols s>=77 are zero in global)
    for (int idx = tid; idx < 80 * 11; idx += 256) {
        const int d = idx / 11, c = idx % 11;
        half8 v = hz;
        if (c < 10)
            v = *(const half8*)&vth[(size_t)bh * (HEAD * 80) + d * 80 + c * 8];
        *(half8*)&Vt[d * LS + c * 8] = v;
    }
    __syncthreads();

    for (int t = 0; t < 4; ++t) {
        // ---- QK^T ----
        floatx4 accs[5] = {};
        #pragma unroll
        for (int st = 0; st < 5; ++st) {
            const _Float16* kr = &Ks[(st * 16 + l16) * LS];
            half8 b0 = *(const half8*)&kr[quad * 8];
            half8 b1 = *(const half8*)&kr[32 + quad * 8];
            half8 b2 = *(const half8*)&kr[64 + quad * 8];
            accs[st] = __builtin_amdgcn_mfma_f32_16x16x32_f16(qa0, b0, accs[st], 0, 0, 0);
            accs[st] = __builtin_amdgcn_mfma_f32_16x16x32_f16(qa1, b1, accs[st], 0, 0, 0);
            accs[st] = __builtin_amdgcn_mfma_f32_16x16x32_f16(qa2, b2, accs[st], 0, 0, 0);
        }
        if (l16 >= 13) {
            accs[4][0] = -1e30f; accs[4][1] = -1e30f;
            accs[4][2] = -1e30f; accs[4][3] = -1e30f;
        }

        // ---- softmax (row = wave*16 + quad*4 + r, cols st*16 + l16) ----
        float recip[4];
        #pragma unroll
        for (int r = 0; r < 4; ++r) {
            float m = accs[0][r];
            #pragma unroll
            for (int st = 1; st < 5; ++st) m = fmaxf(m, accs[st][r]);
            m = fmaxf(m, __shfl_xor(m, 1));
            m = fmaxf(m, __shfl_xor(m, 2));
            m = fmaxf(m, __shfl_xor(m, 4));
            m = fmaxf(m, __shfl_xor(m, 8));
            float l = 0.f;
            const int row = wave * 16 + quad * 4 + r;
            #pragma unroll
            for (int st = 0; st < 5; ++st) {
                float e = __expf(accs[st][r] - m);
                l += e;
                Ps[row * LS + st * 16 + l16] = (_Float16)e;
            }
            l += __shfl_xor(l, 1);
            l += __shfl_xor(l, 2);
            l += __shfl_xor(l, 4);
            l += __shfl_xor(l, 8);
            recip[r] = 1.0f / l;
        }
        __syncthreads();   // Ps visible to all waves

        // prefetch next tile's Q fragments (hidden under PV)
        half8 qn0 = hz, qn1 = hz, qn2 = hz;
        if (t < 3) {
            const _Float16* qn = qp + (size_t)(t + 1) * 64 * EMBED;
            qn0 = *(const half8*)&qn[quad * 8];
            qn1 = *(const half8*)&qn[32 + quad * 8];
            if (quad < 2) qn2 = *(const half8*)&qn[64 + quad * 8];
        }

        // ---- load P fragments, release Ps ----
        const _Float16* pr = &Ps[(wave * 16 + l16) * LS];
        half8 pa0 = *(const half8*)&pr[quad * 8];
        half8 pa1 = *(const half8*)&pr[32 + quad * 8];
        half8 pa2 = (quad < 2) ? *(const half8*)&pr[64 + quad * 8] : hz;
        __syncthreads();   // Ps consumed; next iter may overwrite

        // ---- P @ V^T ----
        floatx4 acco[5] = {};
        #pragma unroll
        for (int dt = 0; dt < 5; ++dt) {
            const _Float16* vr = &Vt[(dt * 16 + l16) * LS];
            half8 b0 = *(const half8*)&vr[quad * 8];
            half8 b1 = *(const half8*)&vr[32 + quad * 8];
            half8 b2 = *(const half8*)&vr[64 + quad * 8];
            acco[dt] = __builtin_amdgcn_mfma_f32_16x16x32_f16(pa0, b0, acco[dt], 0, 0, 0);
            acco[dt] = __builtin_amdgcn_mfma_f32_16x16x32_f16(pa1, b1, acco[dt], 0, 0, 0);
            acco[dt] = __builtin_amdgcn_mfma_f32_16x16x32_f16(pa2, b2, acco[dt], 0, 0, 0);
        }

        // ---- store O ----
        #pragma unroll
        for (int r = 0; r < 4; ++r) {
            const size_t grow = row0 + t * 64 + wave * 16 + quad * 4 + r;
            #pragma unroll
            for (int dt = 0; dt < 5; ++dt)
                oh[grow * EMBED + h * HEAD + dt * 16 + l16] =
                    (_Float16)(acco[dt][r] * recip[r]);
        }

        qa0 = qn0; qa1 = qn1; qa2 = qn2;
    }
}

// ---------------------------------------------------------------------------
extern "C" void kernel_launch(void* const* d_in, const int* in_sizes, int n_in,
                              void* d_out, int out_size, void* d_ws, size_t ws_size,
                              hipStream_t stream)
{
    const float* x  = (const float*)d_in[0];
    const float* y  = (const float*)d_in[1];
    const float* Wq = (const float*)d_in[2];
    const float* bq = (const float*)d_in[3];
    const float* Wk = (const float*)d_in[4];
    const float* bk = (const float*)d_in[5];
    const float* Wv = (const float*)d_in[6];
    const float* bv = (const float*)d_in[7];
    const float* Wo = (const float*)d_in[8];
    const float* bo = (const float*)d_in[9];
    float* out = (float*)d_out;

    const size_t ME = (size_t)MROWS * EMBED;
    _Float16* xh  = (_Float16*)d_ws;                          // [M][640]
    _Float16* qh  = xh + ME;                                  // [M][640]
    _Float16* ah  = qh + ME;                                  // [M][640]
    _Float16* kh  = ah + ME;                                  // [64][77][80]
    _Float16* vth = kh  + (size_t)BATCH * NH * SEQS * HEAD;   // [64][80][80]
    _Float16* wqt = vth + (size_t)BATCH * NH * HEAD * 80;     // [640][640]
    _Float16* wot = wqt + (size_t)EMBED * EMBED;              // [640][640]
    _Float16* yh  = wot + (size_t)EMBED * EMBED;              // [640][768]
    _Float16* wkt = yh  + (size_t)640 * CROSS;                // [640][768]
    _Float16* wvt = wkt + (size_t)EMBED * CROSS;              // [640][768]

    // prep (3 launches)
    transpose_all<<<dim3(EMBED / 32, CROSS / 32, 4), dim3(32, 8), 0, stream>>>(
        Wq, Wo, Wk, Wv, wqt, wot, wkt, wvt);
    cvt_y_zero<<<dim3(440), 256, 0, stream>>>(y, yh, vth);
    cvt_f32_f16<<<dim3(ME / (256 * 8)), 256, 0, stream>>>(x, xh);

    // 1) Q = (x @ Wq + bq) * 1/sqrt(80), f16 out
    gemm_f16<true><<<dim3(EMBED / 128, MROWS / 128), 256, 0, stream>>>(
        xh, wqt, bq, qh, MROWS, EMBED, EMBED, 0.11180339887498949f);
    // 2) K,V projections via MFMA -> attention layouts
    kv_gemm<<<dim3(EMBED / 64, 640 / 64, 2), 256, 0, stream>>>(
        yh, wkt, wvt, bk, bv, kh, vth);
    // 3) MFMA attention: persistent K/V, 256 q-rows per block
    attn_mfma<<<dim3(SEQT / 256, BATCH * NH), 256, 0, stream>>>(qh, kh, vth, ah);
    // 4) out = attn_out @ Wo + bo (fp32 out)
    gemm_f16<false><<<dim3(EMBED / 128, MROWS / 128), 256, 0, stream>>>(
        ah, wot, bo, out, MROWS, EMBED, EMBED, 1.0f);
}